// Round 7
// baseline (492.557 us; speedup 1.0000x reference)
//
#include <hip/hip_runtime.h>

// Problem constants (from reference)
constexpr int NPIX  = 1024 * 1024;    // pixels
constexpr int NB    = 16;             // batch replication factor
constexpr int BLOCK = 256;
constexpr int MAPF4 = NPIX * 3 / 4;   // float4s per batch image = 786432
constexpr int CHUNKS = MAPF4 / BLOCK; // 3072 blocks per image

typedef float vfloat4 __attribute__((ext_vector_type(4)));

// Wire dtypes (prior session): verts/bary f32, faces/p2f int32, out f32.
// out(n,h,w,d) is batch-invariant (reference gathers all batches from
// batch-0 face attrs; batch-0 packing offset is 0).
//
// R7 = R4's grid structure with R4's two bugs removed.
// Counter-verified history of this design space:
//   R2: NT stores at 48B lane stride -> partial lines unmerged at HBM
//       (WRITE 1.82x, 2.6 TB/s). Lane-dense stores are mandatory.
//   R4: one-image-per-block (ideal sequential stream) BUT runtime-indexed
//       r[k]=A[ck]/B[ck] arrays -> scratch (VGPR 20->12, WRITE 513 MB,
//       FETCH 67 MB incl. scratch re-reads) -> 388 us. The structure was
//       never actually measured clean.
//   R5/R6: compute-once + 16-stream stores (NT/cached): clean WRITE but
//       ~70-80 us — the 12 MiB (3*2^22)-stride interleave defeats DRAM row
//       locality; L2 sorting (R6) recovered only ~6 us.
// R7: grid (chunk, image) x-fastest -> resident window writes ONE image
// sequentially (fillBuffer shape, measured 6.5-6.7 TB/s). Interpolation is
// recomputed per image: inputs (~17 MB) are LLC-resident (R2: 1x pass
// fetched only 9 MB), VALU cost <10%. Scalars only — no scratch.
__global__ __launch_bounds__(BLOCK) void uv_fused(
    const float* __restrict__ verts,   // (16, 6890, 3) f32 — only batch 0 read
    const int*   __restrict__ faces,   // (13776, 3) int32
    const int*   __restrict__ p2f,     // (H, W) int32
    const float* __restrict__ bary,    // (H, W, 3) f32
    float*       __restrict__ out)     // (16, H, W, 3) f32
{
    const int j = blockIdx.x * BLOCK + threadIdx.x;  // float4 idx within image
    const int n = blockIdx.y;                        // image (batch) index
    // gridDim.x * BLOCK == MAPF4 exactly; no tail check needed.

    const int F = 4 * j;          // first float index in the image
    const int p = F / 3;          // first pixel covered (magic-mul)
    const int c = F - 3 * p;      // component offset within pixel p (0..2)
    // floats [F,F+4) = pixel p comps [c..2] then pixel p+1 comps [0..c].
    // max j = MAPF4-1 -> p+1 = NPIX-1, in bounds.

    const int f0 = p2f[p];
    const int f1 = p2f[p + 1];

    // --- interpolate pixel p -> A0..A2, pixel p+1 -> B0..B2 (SCALARS,
    // rule #20: no runtime-indexed arrays -> no scratch) ---
    float A0 = 0.f, A1 = 0.f, A2 = 0.f;
    float B0 = 0.f, B1 = 0.f, B2 = 0.f;

    if (f0 >= 0) {
        const int v0 = faces[3 * f0 + 0];
        const int v1 = faces[3 * f0 + 1];
        const int v2 = faces[3 * f0 + 2];
        const float w0 = bary[3 * p + 0];
        const float w1 = bary[3 * p + 1];
        const float w2 = bary[3 * p + 2];
        const float* a0 = verts + 3 * v0;   // batch-0 slice (83 KB, cache-hot)
        const float* a1 = verts + 3 * v1;
        const float* a2 = verts + 3 * v2;
        A0 = w0 * a0[0] + w1 * a1[0] + w2 * a2[0];
        A1 = w0 * a0[1] + w1 * a1[1] + w2 * a2[1];
        A2 = w0 * a0[2] + w1 * a1[2] + w2 * a2[2];
    }
    if (f1 >= 0) {
        const int v0 = faces[3 * f1 + 0];
        const int v1 = faces[3 * f1 + 1];
        const int v2 = faces[3 * f1 + 2];
        const float w0 = bary[3 * (p + 1) + 0];
        const float w1 = bary[3 * (p + 1) + 1];
        const float w2 = bary[3 * (p + 1) + 2];
        const float* a0 = verts + 3 * v0;
        const float* a1 = verts + 3 * v1;
        const float* a2 = verts + 3 * v2;
        B0 = w0 * a0[0] + w1 * a1[0] + w2 * a2[0];
        B1 = w0 * a0[1] + w1 * a1[1] + w2 * a2[1];
        B2 = w0 * a0[2] + w1 * a1[2] + w2 * a2[2];
    }

    // Branchless component permute — pure v_cndmask on scalars.
    //   c=0: A0 A1 A2 B0 | c=1: A1 A2 B0 B1 | c=2: A2 B0 B1 B2
    const bool c0 = (c == 0);
    const bool c1 = (c == 1);
    vfloat4 r;
    r[0] = c0 ? A0 : (c1 ? A1 : A2);
    r[1] = c0 ? A1 : (c1 ? A2 : B0);
    r[2] = c0 ? A2 : (c1 ? B0 : B1);
    r[3] = c0 ? B0 : (c1 ? B1 : B2);

    // Single dense NT store into this block's image; machine-wide write
    // stream is sequential within one image (fillBuffer shape). NT keeps
    // the never-re-read output from evicting the LLC-resident inputs.
    __builtin_nontemporal_store(r, (vfloat4*)out + (size_t)n * MAPF4 + j);
}

extern "C" void kernel_launch(void* const* d_in, const int* in_sizes, int n_in,
                              void* d_out, int out_size, void* d_ws, size_t ws_size,
                              hipStream_t stream) {
    const float* verts = (const float*)d_in[0];   // (16, 6890, 3) f32
    const int*   faces = (const int*)d_in[1];     // (13776, 3) int32
    const int*   p2f   = (const int*)d_in[2];     // (1024, 1024) int32
    const float* bary  = (const float*)d_in[3];   // (1024, 1024, 3) f32
    float*       out   = (float*)d_out;           // (16, 1024, 1024, 3) f32

    dim3 grid(CHUNKS, NB);                        // (3072, 16), x-fastest
    uv_fused<<<grid, dim3(BLOCK), 0, stream>>>(verts, faces, p2f, bary, out);
}

// Round 8
// 224.488 us; speedup vs baseline: 2.1941x; 2.1941x over previous
//
#include <hip/hip_runtime.h>

// Problem constants (from reference)
constexpr int NPIX   = 1024 * 1024;     // pixels
constexpr int NB     = 16;              // batch replication factor
constexpr int PPT    = 4;               // pixels per thread (phase 1)
constexpr int BLOCK1 = 1024;            // phase-1 block (16 waves, 1 block/CU w/ 83KB LDS)
constexpr int BLOCK2 = 256;             // phase-2 block
constexpr int MAPF4  = NPIX * 3 / 4;    // float4s per batch image = 786432
constexpr int REPF4  = (NB - 1) * MAPF4;// float4s written by phase 2
constexpr int NV3    = 6890 * 3;        // floats in batch-0 verts slice = 20670 (82.7 KB)

typedef float vfloat4 __attribute__((ext_vector_type(4)));

// Wire dtypes (prior session): verts/bary f32, faces/p2f int32, out f32.
// out(n,h,w,d) is batch-invariant (reference gathers all batches from
// batch-0 face attrs; batch-0 packing offset is 0).
//
// R8: REVERT to the proven two-phase structure (230.2 us e2e baseline).
// The fused family is falsified by counters:
//   R7 (clean one-image-per-block fused): WRITE 1.00x, FETCH 9.5 MB,
//   no scratch — yet 334.8 us @ 630 GB/s, VALU 8.6%, occ 83%. Bottleneck
//   is the divergent faces->verts gather chain (TA/L1-serialized),
//   ~21 us per image pass, recomputed 16x. Compute must happen ONCE.
//   R5/R6: compute-once + 16-stream stores = 12 MiB-stride interleave,
//   ~70-80 us (DRAM row thrash; L2 sorting recovered only 6 us).
// => compute once (phase 1) + single-image sequential stores (phase 2).
//
// Phase-1 change vs baseline: verts table (83 KB) staged in LDS. The
// gather's 2nd level missed L1 (83 KB table vs 32 KB L1, random idx) and
// serialized in the TA; LDS serves 64 divergent lanes at 32 banks/cycle
// (~2-way conflicts free). Block=1024 keeps 16 waves/CU for latency hiding.
__global__ __launch_bounds__(BLOCK1) void uv_compute_map(
    const float* __restrict__ verts,   // (16, 6890, 3) f32 — only batch 0 read
    const int*   __restrict__ faces,   // (13776, 3) int32
    const int*   __restrict__ p2f,     // (H, W) int32
    const float* __restrict__ bary,    // (H, W, 3) f32
    float*       __restrict__ out)     // batch 0 slice: (H, W, 3) f32
{
    __shared__ float vlds[NV3];
    // Coalesced staging: 21 iterations of dword loads, 83 KB from L2/LLC.
    for (int i = threadIdx.x; i < NV3; i += BLOCK1)
        vlds[i] = verts[i];
    __syncthreads();

    const int t  = blockIdx.x * BLOCK1 + threadIdx.x;
    const int p0 = t * PPT;                        // first pixel of this thread

    const int4 fi = *(const int4*)(p2f + p0);      // 16B aligned (16*t)
    const int fidx[PPT] = {fi.x, fi.y, fi.z, fi.w};

    const float4* b4 = (const float4*)(bary + (size_t)p0 * 3); // 48*t, aligned
    const float4 bv0 = b4[0], bv1 = b4[1], bv2 = b4[2];
    const float b[PPT * 3] = {bv0.x, bv0.y, bv0.z, bv0.w,
                              bv1.x, bv1.y, bv1.z, bv1.w,
                              bv2.x, bv2.y, bv2.z, bv2.w};

    alignas(16) float res[PPT * 3];
    #pragma unroll
    for (int i = 0; i < PPT; ++i) {
        const int f = fidx[i];
        float o0 = 0.f, o1 = 0.f, o2 = 0.f;
        if (f >= 0) {
            const int v0 = 3 * faces[3 * f + 0];
            const int v1 = 3 * faces[3 * f + 1];
            const int v2 = 3 * faces[3 * f + 2];
            const float w0 = b[3 * i + 0];
            const float w1 = b[3 * i + 1];
            const float w2 = b[3 * i + 2];
            o0 = w0 * vlds[v0 + 0] + w1 * vlds[v1 + 0] + w2 * vlds[v2 + 0];
            o1 = w0 * vlds[v0 + 1] + w1 * vlds[v1 + 1] + w2 * vlds[v2 + 1];
            o2 = w0 * vlds[v0 + 2] + w1 * vlds[v1 + 2] + w2 * vlds[v2 + 2];
        }
        res[3 * i + 0] = o0;     // compile-time indices only (rule #20)
        res[3 * i + 1] = o1;
        res[3 * i + 2] = o2;
    }

    // Cached stores: 3 float4s at 48B lane stride merge in L2 (12.6 MB total).
    float4* dst = (float4*)(out + (size_t)p0 * 3);
    const float4* r4 = (const float4*)res;
    dst[0] = r4[0];
    dst[1] = r4[1];
    dst[2] = r4[2];
}

// Phase 2: byte-identical to the 230.2 us baseline. Purely sequential
// NT stores (fillBuffer shape, 6.5 TB/s); src = tid % MAPF4 from the
// LLC-resident 12.6 MB map, 15x reuse.
__global__ __launch_bounds__(BLOCK2) void uv_replicate(
    const vfloat4* __restrict__ map,   // out batch 0, read-only here
    vfloat4*       __restrict__ dst)   // out + MAPF4 (batches 1..15)
{
    const int tid = blockIdx.x * blockDim.x + threadIdx.x;
    if (tid >= REPF4) return;
    const int m = tid % MAPF4;                 // magic-mul, ~4 VALU ops
    const vfloat4 v = map[m];
    __builtin_nontemporal_store(v, dst + tid); // streaming store, never re-read
}

extern "C" void kernel_launch(void* const* d_in, const int* in_sizes, int n_in,
                              void* d_out, int out_size, void* d_ws, size_t ws_size,
                              hipStream_t stream) {
    const float* verts = (const float*)d_in[0];   // (16, 6890, 3) f32
    const int*   faces = (const int*)d_in[1];     // (13776, 3) int32
    const int*   p2f   = (const int*)d_in[2];     // (1024, 1024) int32
    const float* bary  = (const float*)d_in[3];   // (1024, 1024, 3) f32
    float*       out   = (float*)d_out;           // (16, 1024, 1024, 3) f32

    const int grid1 = NPIX / PPT / BLOCK1;        // 256 blocks
    uv_compute_map<<<grid1, BLOCK1, 0, stream>>>(verts, faces, p2f, bary, out);

    const int grid2 = (REPF4 + BLOCK2 - 1) / BLOCK2; // 46080 blocks
    uv_replicate<<<grid2, BLOCK2, 0, stream>>>((const vfloat4*)out,
                                               (vfloat4*)out + MAPF4);
}